// Round 5
// baseline (413.339 us; speedup 1.0000x reference)
//
#include <hip/hip_runtime.h>
#include <cstdint>
#include <cstddef>

#define M_DIM 8192
#define N_DIM 4096
#define K_DIM 4096

// fallback-path tile (128x128, verified)
#define BM 128
#define BN 128
#define BK 128

// fast-path tile
#define BM2 256
#define BN2 256
#define BK2 128
#define NKT (K_DIM / BK2)   // 32

typedef int int32x4  __attribute__((ext_vector_type(4)));
typedef int int32x16 __attribute__((ext_vector_type(16)));

// ws layout:
//   int32 header (64 KB):
//     [0] = flagA (1 -> source already packed int8, 0 -> widened int32)
//     [1] = flagB
//     [16 .. 16+N)      qb (shifted bias)
//     [16+N .. 16+2N)   int_scale
//     [16+2N .. 16+3N)  frac_bits
//   byte 65536:           A8  (M*K int8)  (used when flagA==0)
//   byte 65536 + M*K:     W8  (N*K int8)  (used when flagB==0)

typedef __attribute__((address_space(1))) const void* gas_cptr;
typedef __attribute__((address_space(3))) void* las_ptr;

__device__ __forceinline__ void async_copy16(const void* g, void* l) {
    __builtin_amdgcn_global_load_lds((gas_cptr)g, (las_ptr)l, 16, 0, 0);
}

__device__ __forceinline__ int32x4 pack16(const int* p) {
    const int32x4* v = (const int32x4*)p;
    int32x4 w0 = v[0], w1 = v[1], w2 = v[2], w3 = v[3];
    int32x4 r;
    r.x = (w0.x & 0xFF) | ((w0.y & 0xFF) << 8) | ((w0.z & 0xFF) << 16) | (w0.w << 24);
    r.y = (w1.x & 0xFF) | ((w1.y & 0xFF) << 8) | ((w1.z & 0xFF) << 16) | (w1.w << 24);
    r.z = (w2.x & 0xFF) | ((w2.y & 0xFF) << 8) | ((w2.z & 0xFF) << 16) | (w2.w << 24);
    r.w = (w3.x & 0xFF) | ((w3.y & 0xFF) << 8) | ((w3.z & 0xFF) << 16) | (w3.w << 24);
    return r;
}

__global__ void ql_detect_kernel(const int* a, const int* b, int* ws) {
    int t = threadIdx.x;  // 64 threads
    int fa = 0, fb = 0;
    for (int i = t; i < 4096; i += 64) {
        int va = a[i]; if (va > 127 || va < -128) fa = 1;
        int vb = b[i]; if (vb > 127 || vb < -128) fb = 1;
    }
    unsigned long long ba = __ballot(fa);
    unsigned long long bb = __ballot(fb);
    if (t == 0) { ws[0] = ba ? 1 : 0; ws[1] = bb ? 1 : 0; }
}

// Merged pack: grid-stride over output dwords, W segment then A segment.
// Loads: int32x4 at unit lane stride (1 KB contiguous per wave per instr),
// non-temporal (the widened int32 source is read once — keep it out of L2/L3
// so the packed A8/W8 written here stay resident for the GEMM).
__global__ __launch_bounds__(256)
void ql_pack2_kernel(const void* wsrc, int* wdst, const void* asrc, int* adst,
                     const int* ws) {
    const int fA = __builtin_amdgcn_readfirstlane(ws[0]);
    const int fW = __builtin_amdgcn_readfirstlane(ws[1]);
    const long ndwW = (long)N_DIM * K_DIM / 4;
    const long ndwA = (long)M_DIM * K_DIM / 4;
    const long nW = fW ? 0 : ndwW;
    const long nA = fA ? 0 : ndwA;
    const long total = nW + nA;
    const long stride = (long)gridDim.x * 256;
    for (long c = (long)blockIdx.x * 256 + threadIdx.x; c < total; c += stride) {
        const int32x4* src;
        int* dst;
        long i;
        if (c < nW) { src = (const int32x4*)wsrc; dst = wdst; i = c; }
        else        { src = (const int32x4*)asrc; dst = adst; i = c - nW; }
        int32x4 v = __builtin_nontemporal_load(&src[i]);
        dst[i] = (v.x & 0xFF) | ((v.y & 0xFF) << 8) | ((v.z & 0xFF) << 16) | (v.w << 24);
    }
}

// Fast-path prep: rowsum + requant params from flag-selected int8 weights.
__global__ void ql_prep8_kernel(const void* worig, const int8_t* w8p, const int* qbias,
                                const float* wscale, int* ws) {
    const int fb = __builtin_amdgcn_readfirstlane(ws[1]);
    const int8_t* w8 = fb ? (const int8_t*)worig : w8p;

    const int lane = threadIdx.x & 63;
    const int wid  = threadIdx.x >> 6;
    const int n = blockIdx.x * 4 + wid;

    const int32x4* row = (const int32x4*)(w8 + (size_t)n * K_DIM);
    int s = 0;
    for (int c = lane; c < K_DIM / 16; c += 64) {
        int32x4 v = row[c];
#pragma unroll
        for (int j = 0; j < 4; ++j) {
            int w = (j == 0) ? v.x : (j == 1) ? v.y : (j == 2) ? v.z : v.w;
            s += (int)(int8_t)(w) + (int)(int8_t)(w >> 8)
               + (int)(int8_t)(w >> 16) + (w >> 24);
        }
    }
#pragma unroll
    for (int off = 32; off > 0; off >>= 1) s += __shfl_down(s, off, 64);

    if (lane == 0) {
        ws[16 + n] = qbias[n] + 3 * s;                       // qbias - rowsum*Zin, Zin=-3
        float folded = (0.05f * wscale[n]) / 0.1f;           // in (0,1)
        int fbits = (int)(7.0f - ceilf(log2f(folded)));
        int isc = (int)rintf(folded * exp2f((float)fbits));  // nearest-even == np.round
        ws[16 + N_DIM + n] = isc;
        ws[16 + 2 * N_DIM + n] = fbits;
    }
}

// Fallback prep (ws too small): reads original W, flag-based.
__global__ void ql_prep_kernel(const void* wptr, const int* qbias,
                               const float* wscale, int* ws) {
    const int lane = threadIdx.x & 63;
    const int wid  = threadIdx.x >> 6;
    const int n = blockIdx.x * 4 + wid;
    const int b8 = __builtin_amdgcn_readfirstlane(ws[1]);

    int s = 0;
    if (b8) {
        const int32x4* row = (const int32x4*)((const int8_t*)wptr + (size_t)n * K_DIM);
        for (int c = lane; c < K_DIM / 16; c += 64) {
            int32x4 v = row[c];
#pragma unroll
            for (int j = 0; j < 4; ++j) {
                int w = (j == 0) ? v.x : (j == 1) ? v.y : (j == 2) ? v.z : v.w;
                s += (int)(int8_t)(w) + (int)(int8_t)(w >> 8)
                   + (int)(int8_t)(w >> 16) + (w >> 24);
            }
        }
    } else {
        const int32x4* row = (const int32x4*)((const int*)wptr + (size_t)n * K_DIM);
        for (int c = lane; c < K_DIM / 4; c += 64) {
            int32x4 v = row[c];
            s += v.x + v.y + v.z + v.w;
        }
    }
#pragma unroll
    for (int off = 32; off > 0; off >>= 1) s += __shfl_down(s, off, 64);

    if (lane == 0) {
        ws[16 + n] = qbias[n] + 3 * s;
        float folded = (0.05f * wscale[n]) / 0.1f;
        int fbits = (int)(7.0f - ceilf(log2f(folded)));
        int isc = (int)rintf(folded * exp2f((float)fbits));
        ws[16 + N_DIM + n] = isc;
        ws[16 + 2 * N_DIM + n] = fbits;
    }
}

// Fallback epilogue (128x128 path): requantize acc tile and store int32.
__device__ __forceinline__ void ql_epilogue(int32x4 acc[4][4], const int* ws,
                                            int* out, int bm, int bn,
                                            int wm, int wn, int qm, int qh) {
    const int* qb  = ws + 16;
    const int* isc = ws + 16 + N_DIM;
    const int* fbt = ws + 16 + 2 * N_DIM;
#pragma unroll
    for (int j = 0; j < 4; ++j) {
        const int n_g = bn * BN + wn + j * 16 + qm;
        const int b0 = qb[n_g];
        const int s0 = isc[n_g];
        const int f0 = fbt[n_g];
#pragma unroll
        for (int i = 0; i < 4; ++i) {
            const int m_base = bm * BM + wm + i * 16 + qh * 4;
#pragma unroll
            for (int r = 0; r < 4; ++r) {
                int v = ((r == 0) ? acc[i][j].x : (r == 1) ? acc[i][j].y
                        : (r == 2) ? acc[i][j].z : acc[i][j].w) + b0;
                long long p = (long long)v * (long long)s0;
                int o = (int)(p >> f0) - 5;            // + OUTPUT_ZERO_POINT (-5)
                o = o < -128 ? -128 : (o > 127 ? 127 : o);
                out[(size_t)(m_base + r) * N_DIM + n_g] = o;
            }
        }
    }
}

// ---- fast path: 256x256 GEMM, 32x32x32 i8, 2-phase K-split, counted vmcnt ----
// LDS layout: [buf][khalf][256 rows][4 chunks of 16 B], chunk swizzled
//   phys = c ^ ((row>>1)&3)  -> every ds_read_b128 covers all 8 bank-groups
//   uniformly (8 lanes/group, conflict-free); staging stays wave-contiguous
//   (4 lanes read one row's 64-B global segment, coalesced).
// Ring: tile T phase A computes k-half 0 (kc 0-1), stages (T+1).H0 into buf^1;
//       phase B computes k-half 1, stages (T+1).H1.
// Per phase: s_waitcnt vmcnt(4) (oldest half landed; newest 4 stay in flight),
// s_barrier, 12 ds_reads, 4 stage loads, 16 MFMA (compiler lgkm waits).
// Stage slack = 2 phases (~1900 cy) >> loaded HBM latency. Drain vmcnt(0)
// only in the very last phase.

#define PHASE(BUF, KH, TT, VMC, DOST) do { \
    asm volatile("s_waitcnt vmcnt(" #VMC ")" ::: "memory"); \
    __builtin_amdgcn_s_barrier(); \
    _Pragma("unroll") for (int kr = 0; kr < 2; ++kr) { \
        _Pragma("unroll") for (int ml = 0; ml < 2; ++ml) { \
            aL[ml][kr] = LA[BUF][baseA[KH][kr] + ml * 128]; \
            aH[ml][kr] = LA[BUF][baseA[KH][kr] + 256 + ml * 128]; \
        } \
        b0f[kr] = LB[BUF][baseB[KH][kr]]; \
        b1f[kr] = LB[BUF][baseB[KH][kr] + 128]; \
    } \
    if (DOST) { \
        const size_t so = (size_t)((TT) + 1) * 128 + (KH) * 64; \
        async_copy16(gA + so,          &LA[(BUF) ^ 1][(KH) * 1024 + t]); \
        async_copy16(gA + so + 524288, &LA[(BUF) ^ 1][(KH) * 1024 + 512 + t]); \
        async_copy16(gB + so,          &LB[(BUF) ^ 1][(KH) * 1024 + t]); \
        async_copy16(gB + so + 524288, &LB[(BUF) ^ 1][(KH) * 1024 + 512 + t]); \
    } \
    __builtin_amdgcn_s_setprio(1); \
    _Pragma("unroll") for (int kr = 0; kr < 2; ++kr) \
    _Pragma("unroll") for (int ml = 0; ml < 2; ++ml) { \
        acc[ml][0]     = __builtin_amdgcn_mfma_i32_32x32x32_i8(aL[ml][kr], b0f[kr], acc[ml][0], 0, 0, 0); \
        acc[ml][1]     = __builtin_amdgcn_mfma_i32_32x32x32_i8(aL[ml][kr], b1f[kr], acc[ml][1], 0, 0, 0); \
        acc[2 + ml][0] = __builtin_amdgcn_mfma_i32_32x32x32_i8(aH[ml][kr], b0f[kr], acc[2 + ml][0], 0, 0, 0); \
        acc[2 + ml][1] = __builtin_amdgcn_mfma_i32_32x32x32_i8(aH[ml][kr], b1f[kr], acc[2 + ml][1], 0, 0, 0); \
    } \
    __builtin_amdgcn_s_setprio(0); \
} while (0)

__global__ __launch_bounds__(512, 2)
void ql_gemm8_kernel(const void* a0, const int8_t* a8,
                     const void* b0, const int8_t* w8,
                     const int* ws, int* out) {
    __shared__ int32x4 LA[2][2048];   // [buf][kh*1024 + row*4 + phys]
    __shared__ int32x4 LB[2][2048];   // total 128 KB

    const int fa = __builtin_amdgcn_readfirstlane(ws[0]);
    const int fb = __builtin_amdgcn_readfirstlane(ws[1]);
    const int8_t* aptr = fa ? (const int8_t*)a0 : a8;
    const int8_t* bptr = fb ? (const int8_t*)b0 : w8;

    const int t    = threadIdx.x;     // 512 threads = 8 waves
    const int lane = t & 63;
    const int wid  = t >> 6;          // 0..7
    const int wr   = wid >> 2;        // 0..1  M-half (128 rows)
    const int wc   = wid & 3;         // 0..3  N-quarter (64 cols)
    const int l31  = lane & 31;
    const int hi   = lane >> 5;

    // XCD-chunked bijective swizzle (nwg = 512 = 8 XCD x 64)
    const int flat = blockIdx.y * gridDim.x + blockIdx.x;   // 0..511
    const int xcd  = flat & 7;
    const int lid  = flat >> 3;
    const int g    = lid >> 5;
    const int r    = lid & 31;
    const int bm   = xcd * 4 + g * 2 + (r & 1);   // 0..31
    const int bn   = r >> 1;                      // 0..15

    const int arow0 = bm * BM2;
    const int brow0 = bn * BN2;

    // LDS frag bases (units of int32x4): el = kh*1024 + row*4 + (c ^ ((row>>1)&3)),
    // c = kr*2 + hi. Frag rows = base + l31 with base % 32 == 0 -> f = (l31>>1)&3.
    const int fr31 = (l31 >> 1) & 3;
    int baseA[2][2], baseB[2][2];
#pragma unroll
    for (int kh = 0; kh < 2; ++kh)
#pragma unroll
        for (int kr = 0; kr < 2; ++kr) {
            const int phys = (kr * 2 + hi) ^ fr31;
            baseA[kh][kr] = kh * 1024 + (wr * 128 + l31) * 4 + phys;
            baseB[kh][kr] = kh * 1024 + (wc * 64  + l31) * 4 + phys;
        }

    // Stage source: thread t handles (row0 = t>>2, phys0 = t&3) and row0+128.
    // logical chunk c = phys ^ ((row>>1)&3); (row0+128)>>1 ≡ row0>>1 (mod 4) -> same c.
    const int row0 = t >> 2;
    const int c0   = (t & 3) ^ ((t >> 3) & 3);
    const int8_t* gA = aptr + (size_t)(arow0 + row0) * K_DIM + c0 * 16;
    const int8_t* gB = bptr + (size_t)(brow0 + row0) * K_DIM + c0 * 16;

    int32x16 acc[4][2] = {};
    int32x4 aL[2][2], aH[2][2], b0f[2], b1f[2];

    // prologue: stage T0 both halves -> buf 0 (8 loads/thread outstanding)
#pragma unroll
    for (int kh = 0; kh < 2; ++kh) {
        async_copy16(gA + kh * 64,          &LA[0][kh * 1024 + t]);
        async_copy16(gA + kh * 64 + 524288, &LA[0][kh * 1024 + 512 + t]);
        async_copy16(gB + kh * 64,          &LB[0][kh * 1024 + t]);
        async_copy16(gB + kh * 64 + 524288, &LB[0][kh * 1024 + 512 + t]);
    }

#pragma unroll 1
    for (int T = 0; T < NKT - 2; T += 2) {
        PHASE(0, 0, T, 4, true);
        PHASE(0, 1, T, 4, true);
        PHASE(1, 0, T + 1, 4, true);
        PHASE(1, 1, T + 1, 4, true);
    }
    PHASE(0, 0, NKT - 2, 4, true);
    PHASE(0, 1, NKT - 2, 4, true);
    PHASE(1, 0, NKT - 1, 4, false);
    PHASE(1, 1, NKT - 1, 0, false);

    // epilogue: requantize + non-temporal store
    // (C/D map: col=lane&31, row=(reg&3)+8*(reg>>2)+4*hi)
    const int* qb  = ws + 16;
    const int* isc = ws + 16 + N_DIM;
    const int* fbt = ws + 16 + 2 * N_DIM;
#pragma unroll
    for (int j = 0; j < 2; ++j) {
        const int n_g = bn * BN2 + wc * 64 + j * 32 + l31;
        const int b0r = qb[n_g];
        const int s0r = isc[n_g];
        const int f0r = fbt[n_g];
#pragma unroll
        for (int i = 0; i < 4; ++i) {
            const int m0 = bm * BM2 + wr * 128 + i * 32 + hi * 4;
#pragma unroll
            for (int reg = 0; reg < 16; ++reg) {
                const int row = (reg & 3) + 8 * (reg >> 2);
                int v = acc[i][j][reg] + b0r;
                long long p = (long long)v * (long long)s0r;
                int o = (int)(p >> f0r) - 5;           // + OUTPUT_ZERO_POINT (-5)
                o = o < -128 ? -128 : (o > 127 ? 127 : o);
                __builtin_nontemporal_store(o, &out[(size_t)(m0 + row) * N_DIM + n_g]);
            }
        }
    }
}

// Fallback (ws too small): verified 128x128 kernel, packs in-loop.
__global__ __launch_bounds__(256)
void ql_gemm_fb_kernel(const void* aptr, const void* bptr, const int* ws, int* out) {
    __shared__ int32x4 Als[BM * BK / 16];
    __shared__ int32x4 Bls[BN * BK / 16];

    const int a8 = __builtin_amdgcn_readfirstlane(ws[0]);
    const int b8 = __builtin_amdgcn_readfirstlane(ws[1]);

    const int t    = threadIdx.x;
    const int lane = t & 63;
    const int wid  = t >> 6;
    const int bn = blockIdx.x;
    const int bm = blockIdx.y;

    const int wm = (wid >> 1) * 64;
    const int wn = (wid & 1) * 64;
    const int qm = lane & 15;
    const int qh = lane >> 4;

    int32x4 acc[4][4] = {};

    for (int kt = 0; kt < K_DIM / BK; ++kt) {
        __syncthreads();
        const int k0 = kt * BK;
#pragma unroll
        for (int r = 0; r < 4; ++r) {
            const int c    = r * 256 + t;
            const int row  = c >> 3;
            const int colg = (c & 7) ^ (row & 7);
            const size_t offA = (size_t)(bm * BM + row) * K_DIM + k0 + colg * 16;
            const size_t offB = (size_t)(bn * BN + row) * K_DIM + k0 + colg * 16;
            if (a8) async_copy16((const int8_t*)aptr + offA, &Als[c]);
            else    Als[c] = pack16((const int*)aptr + offA);
            if (b8) async_copy16((const int8_t*)bptr + offB, &Bls[c]);
            else    Bls[c] = pack16((const int*)bptr + offB);
        }
        __syncthreads();

#pragma unroll
        for (int s = 0; s < 2; ++s) {
            const int colk = s * 4 + qh;
            int32x4 af[4], bf[4];
#pragma unroll
            for (int i = 0; i < 4; ++i) {
                const int ra = wm + i * 16 + qm;
                const int rb = wn + i * 16 + qm;
                af[i] = Als[ra * 8 + (colk ^ (ra & 7))];
                bf[i] = Bls[rb * 8 + (colk ^ (rb & 7))];
            }
#pragma unroll
            for (int i = 0; i < 4; ++i)
#pragma unroll
                for (int j = 0; j < 4; ++j)
                    acc[i][j] = __builtin_amdgcn_mfma_i32_16x16x64_i8(
                        af[i], bf[j], acc[i][j], 0, 0, 0);
        }
    }
    ql_epilogue(acc, ws, out, bm, bn, wm, wn, qm, qh);
}

extern "C" void kernel_launch(void* const* d_in, const int* in_sizes, int n_in,
                              void* d_out, int out_size, void* d_ws, size_t ws_size,
                              hipStream_t stream) {
    const void* qin    = d_in[0];
    const void* qwt    = d_in[1];
    const int* qbias   = (const int*)d_in[2];
    const float* wscal = (const float*)d_in[3];
    int* ws  = (int*)d_ws;
    int* out = (int*)d_out;

    hipLaunchKernelGGL(ql_detect_kernel, dim3(1), dim3(64), 0, stream,
                       (const int*)qin, (const int*)qwt, ws);

    const size_t need = 65536 + (size_t)M_DIM * K_DIM + (size_t)N_DIM * K_DIM;
    if (ws_size >= need) {
        int8_t* a8 = (int8_t*)d_ws + 65536;
        int8_t* w8 = a8 + (size_t)M_DIM * K_DIM;
        const long ndwT = (long)M_DIM * K_DIM / 4 + (long)N_DIM * K_DIM / 4;
        hipLaunchKernelGGL(ql_pack2_kernel, dim3((unsigned)(ndwT / (256 * 4))), dim3(256),
                           0, stream, qwt, (int*)w8, qin, (int*)a8, ws);
        hipLaunchKernelGGL(ql_prep8_kernel, dim3(N_DIM / 4), dim3(256), 0, stream,
                           qwt, w8, qbias, wscal, ws);
        hipLaunchKernelGGL(ql_gemm8_kernel, dim3(N_DIM / BN2, M_DIM / BM2), dim3(512),
                           0, stream, qin, a8, qwt, w8, ws, out);
    } else {
        hipLaunchKernelGGL(ql_prep_kernel, dim3(N_DIM / 4), dim3(256), 0, stream,
                           qwt, qbias, wscal, ws);
        hipLaunchKernelGGL(ql_gemm_fb_kernel, dim3(N_DIM / BN, M_DIM / BM), dim3(256), 0, stream,
                           qin, qwt, ws, out);
    }
}

// Round 7
// 412.934 us; speedup vs baseline: 1.0010x; 1.0010x over previous
//
#include <hip/hip_runtime.h>
#include <cstdint>
#include <cstddef>

#define M_DIM 8192
#define N_DIM 4096
#define K_DIM 4096

// fallback-path tile (128x128, verified)
#define BM 128
#define BN 128
#define BK 128

// fast-path tile
#define BM2 256
#define BN2 256
#define BK2 128
#define NKT (K_DIM / BK2)   // 32

typedef int int32x4  __attribute__((ext_vector_type(4)));
typedef int int32x16 __attribute__((ext_vector_type(16)));

// ws layout:
//   int32 header (64 KB):
//     [0] = flagA (1 -> source already packed int8, 0 -> widened int32)
//     [1] = flagB
//     [16 .. 16+N)      qb (shifted bias)
//     [16+N .. 16+2N)   int_scale
//     [16+2N .. 16+3N)  frac_bits
//   byte 65536:           A8  (M*K int8)  (used when flagA==0)
//   byte 65536 + M*K:     W8  (N*K int8)  (used when flagB==0)

typedef __attribute__((address_space(1))) const void* gas_cptr;
typedef __attribute__((address_space(3))) void* las_ptr;

__device__ __forceinline__ void async_copy16(const void* g, void* l) {
    __builtin_amdgcn_global_load_lds((gas_cptr)g, (las_ptr)l, 16, 0, 0);
}

__device__ __forceinline__ int32x4 pack16(const int* p) {
    const int32x4* v = (const int32x4*)p;
    int32x4 w0 = v[0], w1 = v[1], w2 = v[2], w3 = v[3];
    int32x4 r;
    r.x = (w0.x & 0xFF) | ((w0.y & 0xFF) << 8) | ((w0.z & 0xFF) << 16) | (w0.w << 24);
    r.y = (w1.x & 0xFF) | ((w1.y & 0xFF) << 8) | ((w1.z & 0xFF) << 16) | (w1.w << 24);
    r.z = (w2.x & 0xFF) | ((w2.y & 0xFF) << 8) | ((w2.z & 0xFF) << 16) | (w2.w << 24);
    r.w = (w3.x & 0xFF) | ((w3.y & 0xFF) << 8) | ((w3.z & 0xFF) << 16) | (w3.w << 24);
    return r;
}

__global__ void ql_detect_kernel(const int* a, const int* b, int* ws) {
    int t = threadIdx.x;  // 64 threads
    int fa = 0, fb = 0;
    for (int i = t; i < 4096; i += 64) {
        int va = a[i]; if (va > 127 || va < -128) fa = 1;
        int vb = b[i]; if (vb > 127 || vb < -128) fb = 1;
    }
    unsigned long long ba = __ballot(fa);
    unsigned long long bb = __ballot(fb);
    if (t == 0) { ws[0] = ba ? 1 : 0; ws[1] = bb ? 1 : 0; }
}

// Merged pack + W-prep: block < PACK_WBLK handles exactly one W row (1024
// packed dwords) — packs it AND computes rowsum + requant params inline
// (the int32 source values ARE the int8 values, so sum them directly).
// Blocks >= PACK_WBLK pack the A segment. Unit-lane-stride loads, 4-B
// coalesced stores. Early-exit per segment when the source is already int8.
#define PACK_WBLK 4096   // = N_DIM rows
#define PACK_ABLK 8192   // = M*K/4/1024
__global__ __launch_bounds__(256)
void ql_pack2_kernel(const void* wsrc, int* wdst, const void* asrc, int* adst,
                     const int* qbias, const float* wscale, int* ws) {
    __shared__ int red[4];
    const int fA = __builtin_amdgcn_readfirstlane(ws[0]);
    const int fW = __builtin_amdgcn_readfirstlane(ws[1]);
    const int bid = blockIdx.x;
    const int tid = threadIdx.x;
    if (bid < PACK_WBLK) {
        if (fW) return;                      // W already int8; prep8 handles params
        const int n = bid;                   // W row index
        const int32x4* src = (const int32x4*)wsrc + (size_t)n * 1024;
        int* dst = wdst + (size_t)n * 1024;
        int s = 0;
#pragma unroll
        for (int k = 0; k < 4; ++k) {
            const int i = k * 256 + tid;
            int32x4 v = src[i];
            s += v.x + v.y + v.z + v.w;
            dst[i] = (v.x & 0xFF) | ((v.y & 0xFF) << 8) | ((v.z & 0xFF) << 16) | (v.w << 24);
        }
#pragma unroll
        for (int off = 32; off > 0; off >>= 1) s += __shfl_down(s, off, 64);
        if ((tid & 63) == 0) red[tid >> 6] = s;
        __syncthreads();
        if (tid == 0) {
            const int st = red[0] + red[1] + red[2] + red[3];
            ws[16 + n] = qbias[n] + 3 * st;                      // qbias - rowsum*Zin
            float folded = (0.05f * wscale[n]) / 0.1f;           // in (0,1)
            int fbits = (int)(7.0f - ceilf(log2f(folded)));
            int isc = (int)rintf(folded * exp2f((float)fbits));
            ws[16 + N_DIM + n] = isc;
            ws[16 + 2 * N_DIM + n] = fbits;
        }
    } else {
        if (fA) return;
        const long base = (long)(bid - PACK_WBLK) * 1024;
        const int32x4* src = (const int32x4*)asrc + base;
        int* dst = adst + base;
#pragma unroll
        for (int k = 0; k < 4; ++k) {
            const int i = k * 256 + tid;
            int32x4 v = src[i];
            dst[i] = (v.x & 0xFF) | ((v.y & 0xFF) << 8) | ((v.z & 0xFF) << 16) | (v.w << 24);
        }
    }
}

// Fast-path prep: only needed when W arrived already-packed int8
// (otherwise pack computed the params inline). Reads original W.
__global__ void ql_prep8_kernel(const void* worig, const int* qbias,
                                const float* wscale, int* ws) {
    const int fb = __builtin_amdgcn_readfirstlane(ws[1]);
    if (!fb) return;                         // pack already wrote the params

    const int lane = threadIdx.x & 63;
    const int wid  = threadIdx.x >> 6;
    const int n = blockIdx.x * 4 + wid;

    const int32x4* row = (const int32x4*)((const int8_t*)worig + (size_t)n * K_DIM);
    int s = 0;
    for (int c = lane; c < K_DIM / 16; c += 64) {
        int32x4 v = row[c];
#pragma unroll
        for (int j = 0; j < 4; ++j) {
            int w = (j == 0) ? v.x : (j == 1) ? v.y : (j == 2) ? v.z : v.w;
            s += (int)(int8_t)(w) + (int)(int8_t)(w >> 8)
               + (int)(int8_t)(w >> 16) + (w >> 24);
        }
    }
#pragma unroll
    for (int off = 32; off > 0; off >>= 1) s += __shfl_down(s, off, 64);

    if (lane == 0) {
        ws[16 + n] = qbias[n] + 3 * s;                       // qbias - rowsum*Zin, Zin=-3
        float folded = (0.05f * wscale[n]) / 0.1f;           // in (0,1)
        int fbits = (int)(7.0f - ceilf(log2f(folded)));
        int isc = (int)rintf(folded * exp2f((float)fbits));  // nearest-even == np.round
        ws[16 + N_DIM + n] = isc;
        ws[16 + 2 * N_DIM + n] = fbits;
    }
}

// Fallback prep (ws too small): reads original W, flag-based.
__global__ void ql_prep_kernel(const void* wptr, const int* qbias,
                               const float* wscale, int* ws) {
    const int lane = threadIdx.x & 63;
    const int wid  = threadIdx.x >> 6;
    const int n = blockIdx.x * 4 + wid;
    const int b8 = __builtin_amdgcn_readfirstlane(ws[1]);

    int s = 0;
    if (b8) {
        const int32x4* row = (const int32x4*)((const int8_t*)wptr + (size_t)n * K_DIM);
        for (int c = lane; c < K_DIM / 16; c += 64) {
            int32x4 v = row[c];
#pragma unroll
            for (int j = 0; j < 4; ++j) {
                int w = (j == 0) ? v.x : (j == 1) ? v.y : (j == 2) ? v.z : v.w;
                s += (int)(int8_t)(w) + (int)(int8_t)(w >> 8)
                   + (int)(int8_t)(w >> 16) + (w >> 24);
            }
        }
    } else {
        const int32x4* row = (const int32x4*)((const int*)wptr + (size_t)n * K_DIM);
        for (int c = lane; c < K_DIM / 4; c += 64) {
            int32x4 v = row[c];
            s += v.x + v.y + v.z + v.w;
        }
    }
#pragma unroll
    for (int off = 32; off > 0; off >>= 1) s += __shfl_down(s, off, 64);

    if (lane == 0) {
        ws[16 + n] = qbias[n] + 3 * s;
        float folded = (0.05f * wscale[n]) / 0.1f;
        int fbits = (int)(7.0f - ceilf(log2f(folded)));
        int isc = (int)rintf(folded * exp2f((float)fbits));
        ws[16 + N_DIM + n] = isc;
        ws[16 + 2 * N_DIM + n] = fbits;
    }
}

// Fallback epilogue (128x128 path): requantize acc tile and store int32.
__device__ __forceinline__ void ql_epilogue(int32x4 acc[4][4], const int* ws,
                                            int* out, int bm, int bn,
                                            int wm, int wn, int qm, int qh) {
    const int* qb  = ws + 16;
    const int* isc = ws + 16 + N_DIM;
    const int* fbt = ws + 16 + 2 * N_DIM;
#pragma unroll
    for (int j = 0; j < 4; ++j) {
        const int n_g = bn * BN + wn + j * 16 + qm;
        const int b0 = qb[n_g];
        const int s0 = isc[n_g];
        const int f0 = fbt[n_g];
#pragma unroll
        for (int i = 0; i < 4; ++i) {
            const int m_base = bm * BM + wm + i * 16 + qh * 4;
#pragma unroll
            for (int r = 0; r < 4; ++r) {
                int v = ((r == 0) ? acc[i][j].x : (r == 1) ? acc[i][j].y
                        : (r == 2) ? acc[i][j].z : acc[i][j].w) + b0;
                long long p = (long long)v * (long long)s0;
                int o = (int)(p >> f0) - 5;            // + OUTPUT_ZERO_POINT (-5)
                o = o < -128 ? -128 : (o > 127 ? 127 : o);
                out[(size_t)(m_base + r) * N_DIM + n_g] = o;
            }
        }
    }
}

// ---- fast path: 256x256 GEMM, 32x32x32 i8, counted-vmcnt depth-2 ring ----
// LDS: proven zero-conflict geometry (R3/R4): row-major 128-B rows, 8 chunks,
// phys = c ^ f(row), f(row) = (row&7) ^ ((row>>3)&3); stage pre-applies f.
// Ring (NO full drain in loop): prologue stages T0->buf0, T1->buf1.
// Tile T (buf = T&1):
//   s_waitcnt vmcnt(8)   -- waits ONLY for tile T's 8 loads (issued >=1 full
//                           tile ago); tile T+1's 8 newest stay in flight
//   s_barrier            -- whole tile T now visible to all waves
//   24 ds_reads + 32 MFMA (compiler lgkm partial waits interleave)
//   s_barrier            -- all waves done reading buf
//   stage T+2 -> buf     -- overwrite is safe; lands before T+2's vmcnt(8)
// Last tile: vmcnt(0) (own loads, ~2 tiles of slack).

#define TILE2(BUF, TT, VMC, DOST) do { \
    asm volatile("s_waitcnt vmcnt(" #VMC ")" ::: "memory"); \
    __builtin_amdgcn_s_barrier(); \
    _Pragma("unroll") for (int ml = 0; ml < 2; ++ml) \
    _Pragma("unroll") for (int kc = 0; kc < 4; ++kc) \
        afL[ml][kc] = LA[BUF][baseAe[kc] + ml * 256]; \
    _Pragma("unroll") for (int kc = 0; kc < 4; ++kc) \
        bf0[kc] = LB[BUF][baseBe[kc]]; \
    _Pragma("unroll") for (int kc = 0; kc < 4; ++kc) \
        bf1[kc] = LB[BUF][baseBe[kc] + 256]; \
    _Pragma("unroll") for (int ml = 0; ml < 2; ++ml) \
    _Pragma("unroll") for (int kc = 0; kc < 4; ++kc) \
        afH[ml][kc] = LA[BUF][baseAe[kc] + 512 + ml * 256]; \
    __builtin_amdgcn_s_setprio(1); \
    _Pragma("unroll") for (int kc = 0; kc < 4; ++kc) \
    _Pragma("unroll") for (int ml = 0; ml < 2; ++ml) \
        acc[ml][0] = __builtin_amdgcn_mfma_i32_32x32x32_i8(afL[ml][kc], bf0[kc], acc[ml][0], 0, 0, 0); \
    _Pragma("unroll") for (int kc = 0; kc < 4; ++kc) \
    _Pragma("unroll") for (int ml = 0; ml < 2; ++ml) \
        acc[ml][1] = __builtin_amdgcn_mfma_i32_32x32x32_i8(afL[ml][kc], bf1[kc], acc[ml][1], 0, 0, 0); \
    _Pragma("unroll") for (int kc = 0; kc < 4; ++kc) \
    _Pragma("unroll") for (int ml = 0; ml < 2; ++ml) \
        acc[2 + ml][0] = __builtin_amdgcn_mfma_i32_32x32x32_i8(afH[ml][kc], bf0[kc], acc[2 + ml][0], 0, 0, 0); \
    _Pragma("unroll") for (int kc = 0; kc < 4; ++kc) \
    _Pragma("unroll") for (int ml = 0; ml < 2; ++ml) \
        acc[2 + ml][1] = __builtin_amdgcn_mfma_i32_32x32x32_i8(afH[ml][kc], bf1[kc], acc[2 + ml][1], 0, 0, 0); \
    __builtin_amdgcn_s_setprio(0); \
    __builtin_amdgcn_s_barrier(); \
    if (DOST) { \
        _Pragma("unroll") for (int h2 = 0; h2 < 4; ++h2) { \
            async_copy16(gA + (size_t)((TT) + 2) * 128 + (size_t)h2 * 262144, \
                         &LA[BUF][h2 * 512 + t]); \
            async_copy16(gB + (size_t)((TT) + 2) * 128 + (size_t)h2 * 262144, \
                         &LB[BUF][h2 * 512 + t]); \
        } \
    } \
} while (0)

__global__ __launch_bounds__(512, 2)
void ql_gemm8_kernel(const void* a0, const int8_t* a8,
                     const void* b0, const int8_t* w8,
                     const int* ws, int* out) {
    __shared__ int32x4 LA[2][2048];   // 2 x 32 KB
    __shared__ int32x4 LB[2][2048];   // total 128 KB

    const int fa = __builtin_amdgcn_readfirstlane(ws[0]);
    const int fb = __builtin_amdgcn_readfirstlane(ws[1]);
    const int8_t* aptr = fa ? (const int8_t*)a0 : a8;
    const int8_t* bptr = fb ? (const int8_t*)b0 : w8;

    const int t    = threadIdx.x;     // 512 threads = 8 waves
    const int lane = t & 63;
    const int wid  = t >> 6;          // 0..7
    const int wr   = wid >> 2;        // 0..1  M-half (128 rows)
    const int wc   = wid & 3;         // 0..3  N-quarter (64 cols)
    const int l31  = lane & 31;
    const int hi   = lane >> 5;

    // XCD-chunked bijective swizzle (nwg = 512 = 8 XCD x 64)
    const int flat = blockIdx.y * gridDim.x + blockIdx.x;   // 0..511
    const int xcd  = flat & 7;
    const int lid  = flat >> 3;
    const int g    = lid >> 5;
    const int r    = lid & 31;
    const int bm   = xcd * 4 + g * 2 + (r & 1);   // 0..31
    const int bn   = r >> 1;                      // 0..15

    const int arow0 = bm * BM2;
    const int brow0 = bn * BN2;

    // LDS frag bases (units of int32x4). phys = logical ^ f(row),
    // f(row) = (row&7) ^ ((row>>3)&3); for frag rows f = (lane&7) ^ ((l31>>3)&3).
    const int fr = (lane & 7) ^ ((l31 >> 3) & 3);
    int baseAe[4], baseBe[4];
#pragma unroll
    for (int kc = 0; kc < 4; ++kc) {
        const int phys = (kc * 2 + hi) ^ fr;
        baseAe[kc] = (wr * 128 + l31) * 8 + phys;
        baseBe[kc] = (wc * 64  + l31) * 8 + phys;
    }

    // Stage source pre-swizzle: thread t writes phys chunk (t&7) of row
    // h2*64 + (t>>3); logical col = (t&7) ^ f(row), f = ((t>>3)&7) ^ ((t>>6)&3).
    const int colg = (t & 7) ^ ((t >> 3) & 7) ^ ((t >> 6) & 3);
    const int8_t* gA = aptr + (size_t)(arow0 + (t >> 3)) * K_DIM + colg * 16;
    const int8_t* gB = bptr + (size_t)(brow0 + (t >> 3)) * K_DIM + colg * 16;

    int32x16 acc[4][2] = {};
    int32x4 afL[2][4], afH[2][4], bf0[4], bf1[4];

    // prologue: stage T0 -> buf0, T1 -> buf1 (16 loads/thread outstanding)
#pragma unroll
    for (int h2 = 0; h2 < 4; ++h2) {
        async_copy16(gA + (size_t)h2 * 262144, &LA[0][h2 * 512 + t]);
        async_copy16(gB + (size_t)h2 * 262144, &LB[0][h2 * 512 + t]);
    }
#pragma unroll
    for (int h2 = 0; h2 < 4; ++h2) {
        async_copy16(gA + 128 + (size_t)h2 * 262144, &LA[1][h2 * 512 + t]);
        async_copy16(gB + 128 + (size_t)h2 * 262144, &LB[1][h2 * 512 + t]);
    }

#pragma unroll 1
    for (int T = 0; T < NKT - 2; T += 2) {
        TILE2(0, T, 8, true);
        TILE2(1, T + 1, 8, true);
    }
    TILE2(0, NKT - 2, 8, false);
    TILE2(1, NKT - 1, 0, false);

    // epilogue: requantize + non-temporal store
    // (C/D map: col=lane&31, row=(reg&3)+8*(reg>>2)+4*hi)
    const int* qb  = ws + 16;
    const int* isc = ws + 16 + N_DIM;
    const int* fbt = ws + 16 + 2 * N_DIM;
#pragma unroll
    for (int j = 0; j < 2; ++j) {
        const int n_g = bn * BN2 + wc * 64 + j * 32 + l31;
        const int b0r = qb[n_g];
        const int s0r = isc[n_g];
        const int f0r = fbt[n_g];
#pragma unroll
        for (int i = 0; i < 4; ++i) {
            const int m0 = bm * BM2 + wr * 128 + i * 32 + hi * 4;
#pragma unroll
            for (int reg = 0; reg < 16; ++reg) {
                const int row = (reg & 3) + 8 * (reg >> 2);
                int v = acc[i][j][reg] + b0r;
                long long p = (long long)v * (long long)s0r;
                int o = (int)(p >> f0r) - 5;           // + OUTPUT_ZERO_POINT (-5)
                o = o < -128 ? -128 : (o > 127 ? 127 : o);
                __builtin_nontemporal_store(o, &out[(size_t)(m0 + row) * N_DIM + n_g]);
            }
        }
    }
}

// Fallback (ws too small): verified 128x128 kernel, packs in-loop.
__global__ __launch_bounds__(256)
void ql_gemm_fb_kernel(const void* aptr, const void* bptr, const int* ws, int* out) {
    __shared__ int32x4 Als[BM * BK / 16];
    __shared__ int32x4 Bls[BN * BK / 16];

    const int a8 = __builtin_amdgcn_readfirstlane(ws[0]);
    const int b8 = __builtin_amdgcn_readfirstlane(ws[1]);

    const int t    = threadIdx.x;
    const int lane = t & 63;
    const int wid  = t >> 6;
    const int bn = blockIdx.x;
    const int bm = blockIdx.y;

    const int wm = (wid >> 1) * 64;
    const int wn = (wid & 1) * 64;
    const int qm = lane & 15;
    const int qh = lane >> 4;

    int32x4 acc[4][4] = {};

    for (int kt = 0; kt < K_DIM / BK; ++kt) {
        __syncthreads();
        const int k0 = kt * BK;
#pragma unroll
        for (int r = 0; r < 4; ++r) {
            const int c    = r * 256 + t;
            const int row  = c >> 3;
            const int colg = (c & 7) ^ (row & 7);
            const size_t offA = (size_t)(bm * BM + row) * K_DIM + k0 + colg * 16;
            const size_t offB = (size_t)(bn * BN + row) * K_DIM + k0 + colg * 16;
            if (a8) async_copy16((const int8_t*)aptr + offA, &Als[c]);
            else    Als[c] = pack16((const int*)aptr + offA);
            if (b8) async_copy16((const int8_t*)bptr + offB, &Bls[c]);
            else    Bls[c] = pack16((const int*)bptr + offB);
        }
        __syncthreads();

#pragma unroll
        for (int s = 0; s < 2; ++s) {
            const int colk = s * 4 + qh;
            int32x4 af[4], bf[4];
#pragma unroll
            for (int i = 0; i < 4; ++i) {
                const int ra = wm + i * 16 + qm;
                const int rb = wn + i * 16 + qm;
                af[i] = Als[ra * 8 + (colk ^ (ra & 7))];
                bf[i] = Bls[rb * 8 + (colk ^ (rb & 7))];
            }
#pragma unroll
            for (int i = 0; i < 4; ++i)
#pragma unroll
                for (int j = 0; j < 4; ++j)
                    acc[i][j] = __builtin_amdgcn_mfma_i32_16x16x64_i8(
                        af[i], bf[j], acc[i][j], 0, 0, 0);
        }
    }
    ql_epilogue(acc, ws, out, bm, bn, wm, wn, qm, qh);
}

extern "C" void kernel_launch(void* const* d_in, const int* in_sizes, int n_in,
                              void* d_out, int out_size, void* d_ws, size_t ws_size,
                              hipStream_t stream) {
    const void* qin    = d_in[0];
    const void* qwt    = d_in[1];
    const int* qbias   = (const int*)d_in[2];
    const float* wscal = (const float*)d_in[3];
    int* ws  = (int*)d_ws;
    int* out = (int*)d_out;

    hipLaunchKernelGGL(ql_detect_kernel, dim3(1), dim3(64), 0, stream,
                       (const int*)qin, (const int*)qwt, ws);

    const size_t need = 65536 + (size_t)M_DIM * K_DIM + (size_t)N_DIM * K_DIM;
    if (ws_size >= need) {
        int8_t* a8 = (int8_t*)d_ws + 65536;
        int8_t* w8 = a8 + (size_t)M_DIM * K_DIM;
        hipLaunchKernelGGL(ql_pack2_kernel, dim3(PACK_WBLK + PACK_ABLK), dim3(256),
                           0, stream, qwt, (int*)w8, qin, (int*)a8, qbias, wscal, ws);
        hipLaunchKernelGGL(ql_prep8_kernel, dim3(N_DIM / 4), dim3(256), 0, stream,
                           qwt, qbias, wscal, ws);
        hipLaunchKernelGGL(ql_gemm8_kernel, dim3(N_DIM / BN2, M_DIM / BM2), dim3(512),
                           0, stream, qin, a8, qwt, w8, ws, out);
    } else {
        hipLaunchKernelGGL(ql_prep_kernel, dim3(N_DIM / 4), dim3(256), 0, stream,
                           qwt, qbias, wscal, ws);
        hipLaunchKernelGGL(ql_gemm_fb_kernel, dim3(N_DIM / BN, M_DIM / BM), dim3(256), 0, stream,
                           qin, qwt, ws, out);
    }
}